// Round 4
// baseline (539.463 us; speedup 1.0000x reference)
//
#include <hip/hip_runtime.h>
#include <hip/hip_bf16.h>

// Swin window self-attention, fused. fp32 inputs -> bf16 MFMA -> fp32 output.
// B windows (grid-adaptive, nominally 4096), SEQ=49 tokens (padded to 64),
// C=128, H=4 heads x DH=32. One block per window; 4 waves; wave w handles
// output cols [32w,32w+32) for QKV projection (== head w for V) and head w
// for attention.

#define SEQ 49
#define CH 128
#define NH 4
#define DHD 32
#define NTAB 169

typedef __hip_bfloat16 bf16;
typedef __attribute__((ext_vector_type(8))) short bf16x8;  // 8 bf16 = 4 VGPRs
typedef __attribute__((ext_vector_type(4))) float f32x4;

// ---- LDS layout (bf16 element offsets) ----
// Strides padded so MFMA fragment reads are <=2-way bank conflicts (free):
//   [64][128] buffers use stride 136 (272 B) ; [..][64] buffers use stride 72 (144 B)
#define LDQ 136
#define LDP 72
#define OFF_Q    0                       // Q  [64][LDQ]
#define OFF_K    (OFF_Q + 64*LDQ)        // K  [64][LDQ]
#define OFF_VT   (OFF_K + 64*LDQ)        // V^T [128][LDP]  (Vt[d][m])
#define OFF_XP   (OFF_VT + CH*LDP)       // union: X [64][LDQ] then P [4][64][LDP]
#define OFF_TAB  (OFF_XP + NH*64*LDP)    // table, fp32 [169*4] (bf16-slot units)
#define SMEM_ELEMS (OFF_TAB + NTAB*NH*2 + 8)
#define SMEM_BYTES (SMEM_ELEMS * 2)      // ~92.8 KB -> 1 block/CU

__global__ __launch_bounds__(256, 1) void swin_attn_kernel(
    const float* __restrict__ hs,     // [B,49,128] fp32
    const float* __restrict__ amask,  // [B,49,49] fp32
    const float* __restrict__ Wq, const float* __restrict__ bq,
    const float* __restrict__ Wk, const float* __restrict__ bk,
    const float* __restrict__ Wv, const float* __restrict__ bv,
    const float* __restrict__ table,  // [169,4] fp32
    const int*  __restrict__ ridx,    // [2401]
    float* __restrict__ out)          // [B,49,128] fp32
{
    extern __shared__ bf16 smem[];
    const int tid  = threadIdx.x;
    const int b    = blockIdx.x;
    const int wave = tid >> 6;
    const int lane = tid & 63;
    const int quad = lane >> 4;
    const int l    = lane & 15;

    bf16*  sQ  = smem + OFF_Q;
    bf16*  sK  = smem + OFF_K;
    bf16*  sVt = smem + OFF_VT;
    bf16*  sX  = smem + OFF_XP;   // X lives here during projection
    bf16*  sP  = smem + OFF_XP;   // P reuses the region afterwards
    float* sTf = (float*)(smem + OFF_TAB);

    // ---- stage X (fp32 -> bf16, rows 49..63 zeroed) and bias table ----
    for (int i = tid; i < 64*32; i += 256) {
        int row = i >> 5, seg = i & 31;           // seg: 4 floats each
        float4 v = make_float4(0.f, 0.f, 0.f, 0.f);
        if (row < SEQ)
            v = *(const float4*)(hs + ((size_t)b*SEQ + row)*CH + seg*4);
        alignas(8) bf16 t4[4] = {__float2bfloat16(v.x), __float2bfloat16(v.y),
                                 __float2bfloat16(v.z), __float2bfloat16(v.w)};
        *(uint2*)(sX + row*LDQ + seg*4) = *(const uint2*)t4;
    }
    for (int i = tid; i < NTAB*NH; i += 256) sTf[i] = table[i];
    __syncthreads();

    // ---- phase 1: QKV projection  y[n,d] = sum_c X[n,c]*W[d,c] + b[d] ----
    // A-frag: X[m=lane&15 (+16*mt)][k=quad*8+j (+32*kstep)]
    bf16x8 aX[4][4];
#pragma unroll
    for (int mt = 0; mt < 4; ++mt)
#pragma unroll
        for (int k = 0; k < 4; ++k)
            aX[mt][k] = *(const bf16x8*)(sX + (mt*16 + l)*LDQ + k*32 + quad*8);

    const float* Wmat[3] = {Wq, Wk, Wv};
    const float* Bvec[3] = {bq, bk, bv};

#pragma unroll
    for (int which = 0; which < 3; ++which) {
#pragma unroll
        for (int j = 0; j < 2; ++j) {
            const int nt  = wave*2 + j;
            const int col = nt*16 + l;           // output channel d this lane owns
            f32x4 acc[4] = {{0.f,0.f,0.f,0.f},{0.f,0.f,0.f,0.f},
                            {0.f,0.f,0.f,0.f},{0.f,0.f,0.f,0.f}};
#pragma unroll
            for (int k = 0; k < 4; ++k) {
                // B-frag: B[k][n] = W[d=col][c] -> 8 contiguous fp32 in W row
                const float* wr = Wmat[which] + (size_t)col*CH + k*32 + quad*8;
                float4 w0 = *(const float4*)(wr);
                float4 w1 = *(const float4*)(wr + 4);
                alignas(16) bf16 t8[8] = {
                    __float2bfloat16(w0.x), __float2bfloat16(w0.y),
                    __float2bfloat16(w0.z), __float2bfloat16(w0.w),
                    __float2bfloat16(w1.x), __float2bfloat16(w1.y),
                    __float2bfloat16(w1.z), __float2bfloat16(w1.w)};
                bf16x8 bw = *(const bf16x8*)t8;
#pragma unroll
                for (int mt = 0; mt < 4; ++mt)
                    acc[mt] = __builtin_amdgcn_mfma_f32_16x16x32_bf16(
                        aX[mt][k], bw, acc[mt], 0, 0, 0);
            }
            const float bias = Bvec[which][col];
            if (which == 2) {
                // V stored transposed: Vt[d][m]
#pragma unroll
                for (int mt = 0; mt < 4; ++mt)
#pragma unroll
                    for (int r = 0; r < 4; ++r)
                        sVt[col*LDP + mt*16 + quad*4 + r] =
                            __float2bfloat16(acc[mt][r] + bias);
            } else {
                bf16* dst = (which == 0) ? sQ : sK;
#pragma unroll
                for (int mt = 0; mt < 4; ++mt)
#pragma unroll
                    for (int r = 0; r < 4; ++r)
                        dst[(mt*16 + quad*4 + r)*LDQ + col] =
                            __float2bfloat16(acc[mt][r] + bias);
            }
        }
    }
    __syncthreads();

    // ---- phase 2: S = Q K^T / sqrt(DH) + rel_bias + mask ; softmax ----
    const int h = wave;
    bf16x8 aQ[4], bK[4];
#pragma unroll
    for (int t = 0; t < 4; ++t) {
        aQ[t] = *(const bf16x8*)(sQ + (t*16 + l)*LDQ + h*DHD + quad*8);
        bK[t] = *(const bf16x8*)(sK + (t*16 + l)*LDQ + h*DHD + quad*8);
    }
    f32x4 S[4][4]; // [mt(nq tiles)][nt(kv tiles)]
#pragma unroll
    for (int mt = 0; mt < 4; ++mt)
#pragma unroll
        for (int nt = 0; nt < 4; ++nt) {
            f32x4 z = {0.f,0.f,0.f,0.f};
            S[mt][nt] = __builtin_amdgcn_mfma_f32_16x16x32_bf16(aQ[mt], bK[nt], z, 0, 0, 0);
        }

    const float scale = 0.17677669529663687f; // 1/sqrt(32)
    const float* amrow = amask + (size_t)b*(SEQ*SEQ);
#pragma unroll
    for (int mt = 0; mt < 4; ++mt) {
#pragma unroll
        for (int r = 0; r < 4; ++r) {
            const int nq = mt*16 + quad*4 + r;   // query row (D-layout row)
#pragma unroll
            for (int nt = 0; nt < 4; ++nt) {
                const int mk = nt*16 + l;        // kv col (D-layout col)
                float s;
                if (mk < SEQ) {
                    s = S[mt][nt][r] * scale;
                    if (nq < SEQ) {
                        int idx = ridx[nq*SEQ + mk];
                        idx = idx < 0 ? 0 : (idx > NTAB-1 ? NTAB-1 : idx);
                        s += sTf[idx*NH + h] + amrow[nq*SEQ + mk];
                    }
                } else {
                    s = -30000.f;                // mask padding kv
                }
                S[mt][nt][r] = s;
            }
            // row softmax: in-lane over 4 nt, cross-lane over the 16-lane group
            float m = fmaxf(fmaxf(S[mt][0][r], S[mt][1][r]),
                            fmaxf(S[mt][2][r], S[mt][3][r]));
            m = fmaxf(m, __shfl_xor(m, 1));
            m = fmaxf(m, __shfl_xor(m, 2));
            m = fmaxf(m, __shfl_xor(m, 4));
            m = fmaxf(m, __shfl_xor(m, 8));
            float sum = 0.f;
#pragma unroll
            for (int nt = 0; nt < 4; ++nt) {
                float e = __expf(S[mt][nt][r] - m);
                S[mt][nt][r] = e;
                sum += e;
            }
            sum += __shfl_xor(sum, 1);
            sum += __shfl_xor(sum, 2);
            sum += __shfl_xor(sum, 4);
            sum += __shfl_xor(sum, 8);
            const float inv = 1.f / sum;
#pragma unroll
            for (int nt = 0; nt < 4; ++nt)
                sP[h*(64*LDP) + nq*LDP + nt*16 + l] =
                    __float2bfloat16(S[mt][nt][r] * inv);
        }
    }
    __syncthreads();

    // ---- phase 3: O = P V ----
    bf16x8 aP[4][2], bV[2][2];
#pragma unroll
    for (int mt = 0; mt < 4; ++mt)
#pragma unroll
        for (int ks = 0; ks < 2; ++ks)
            aP[mt][ks] = *(const bf16x8*)(sP + h*(64*LDP) + (mt*16 + l)*LDP + ks*32 + quad*8);
#pragma unroll
    for (int nt = 0; nt < 2; ++nt)
#pragma unroll
        for (int ks = 0; ks < 2; ++ks)
            bV[nt][ks] = *(const bf16x8*)(sVt + (h*DHD + nt*16 + l)*LDP + ks*32 + quad*8);

    f32x4 O[4][2] = {{{0.f,0.f,0.f,0.f},{0.f,0.f,0.f,0.f}},
                     {{0.f,0.f,0.f,0.f},{0.f,0.f,0.f,0.f}},
                     {{0.f,0.f,0.f,0.f},{0.f,0.f,0.f,0.f}},
                     {{0.f,0.f,0.f,0.f},{0.f,0.f,0.f,0.f}}};
#pragma unroll
    for (int mt = 0; mt < 4; ++mt)
#pragma unroll
        for (int nt = 0; nt < 2; ++nt)
#pragma unroll
            for (int ks = 0; ks < 2; ++ks)
                O[mt][nt] = __builtin_amdgcn_mfma_f32_16x16x32_bf16(
                    aP[mt][ks], bV[nt][ks], O[mt][nt], 0, 0, 0);

#pragma unroll
    for (int mt = 0; mt < 4; ++mt)
#pragma unroll
        for (int r = 0; r < 4; ++r) {
            const int nq = mt*16 + quad*4 + r;
            if (nq < SEQ) {
#pragma unroll
                for (int nt = 0; nt < 2; ++nt)
                    out[((size_t)b*SEQ + nq)*CH + h*DHD + nt*16 + l] = O[mt][nt][r];
            }
        }
}

extern "C" void kernel_launch(void* const* d_in, const int* in_sizes, int n_in,
                              void* d_out, int out_size, void* d_ws, size_t ws_size,
                              hipStream_t stream) {
    (void)n_in; (void)out_size; (void)d_ws; (void)ws_size;
    const int nwin = in_sizes[0] / (SEQ * CH);   // grid-adaptive window count
    hipFuncSetAttribute(reinterpret_cast<const void*>(swin_attn_kernel),
                        hipFuncAttributeMaxDynamicSharedMemorySize, SMEM_BYTES);
    swin_attn_kernel<<<dim3(nwin), dim3(256), SMEM_BYTES, stream>>>(
        (const float*)d_in[0], (const float*)d_in[1],
        (const float*)d_in[2], (const float*)d_in[3],
        (const float*)d_in[4], (const float*)d_in[5],
        (const float*)d_in[6], (const float*)d_in[7],
        (const float*)d_in[8], (const int*)d_in[9],
        (float*)d_out);
}

// Round 5
// 336.687 us; speedup vs baseline: 1.6023x; 1.6023x over previous
//
#include <hip/hip_runtime.h>
#include <hip/hip_bf16.h>

// Swin window self-attention, fused. fp32 inputs -> bf16 MFMA -> fp32 output.
// R5: occupancy round. LDS 92.8->53.2 KB (3 blocks/CU = 12 waves/CU):
//  - X A-frags loaded directly from global (no LDS staging, no first barrier)
//  - rel-pos bias precomputed to d_ws as bias_pad[h][64][64] by a tiny kernel
//    (kills the ridx->table dependent gather chain in the hot kernel)
//  - P overlays the dead Q+K region (planes shrunk to 52 rows/head), one
//    extra barrier after aQ/bK fragment loads
//  - mask+bias epilogue loads double-buffered per-mt (prefetch 1 tile ahead)

#define SEQ 49
#define CH 128
#define NH 4
#define DHD 32
#define NTAB 169

typedef __hip_bfloat16 bf16;
typedef __attribute__((ext_vector_type(8))) short bf16x8;  // 8 bf16 = 4 VGPRs
typedef __attribute__((ext_vector_type(4))) float f32x4;

// LDS (bf16 elems). Row strides multiple-of-8 elems (16 B) for b128 reads,
// not multiple of 64 (128 B) to rotate banks.
#define LDQ 136
#define LDP 72
#define PROWS 52                       // P plane rows (>=49; reads past end stay in Q+K region)
#define OFF_Q  0                       // Q  [64][136] = 8704
#define OFF_K  (64*LDQ)                // K  [64][136] = 8704
#define OFF_VT (2*64*LDQ)              // Vt [128][72] = 9216  (Vt[d][m])
#define SMEM_ELEMS (OFF_VT + CH*LDP)   // 26624 elems
#define SMEM_BYTES (SMEM_ELEMS*2)      // 53248 B -> 3 blocks/CU (3*53248<160K)

__device__ __forceinline__ bf16x8 pack8(float4 a, float4 b) {
    alignas(16) bf16 t[8] = {
        __float2bfloat16(a.x), __float2bfloat16(a.y),
        __float2bfloat16(a.z), __float2bfloat16(a.w),
        __float2bfloat16(b.x), __float2bfloat16(b.y),
        __float2bfloat16(b.z), __float2bfloat16(b.w)};
    return *(const bf16x8*)t;
}

__global__ void bias_precompute_kernel(const float* __restrict__ table,
                                       const int* __restrict__ ridx,
                                       float* __restrict__ bias_pad) {
    int i = blockIdx.x*256 + threadIdx.x;    // bias_pad[h][nq:64][mk:64]
    if (i >= NH*64*64) return;
    int h = i >> 12, nq = (i >> 6) & 63, mk = i & 63;
    float v = 0.f;
    if (nq < SEQ && mk < SEQ) {
        int idx = ridx[nq*SEQ + mk];
        idx = idx < 0 ? 0 : (idx > NTAB-1 ? NTAB-1 : idx);
        v = table[idx*NH + h];
    }
    bias_pad[i] = v;
}

template<bool USEWS>
__global__ __launch_bounds__(256, 3) void swin_attn_kernel(
    const float* __restrict__ hs,     // [B,49,128]
    const float* __restrict__ amask,  // [B,49,49]
    const float* __restrict__ Wq, const float* __restrict__ bq,
    const float* __restrict__ Wk, const float* __restrict__ bk,
    const float* __restrict__ Wv, const float* __restrict__ bv,
    const float* __restrict__ table,  // [169,4]
    const int*  __restrict__ ridx,    // [2401]
    const float* __restrict__ bias_pad, // [4][64][64] (USEWS)
    float* __restrict__ out)          // [B,49,128]
{
    extern __shared__ bf16 smem[];
    const int tid  = threadIdx.x;
    const int b    = blockIdx.x;
    const int wave = tid >> 6;
    const int lane = tid & 63;
    const int quad = lane >> 4;
    const int l    = lane & 15;

    bf16* sQ  = smem + OFF_Q;
    bf16* sK  = smem + OFF_K;
    bf16* sVt = smem + OFF_VT;
    bf16* sP  = smem;                 // overlays Q+K after B2; [4][PROWS][LDP]

    // ---- X A-frags direct from global (fp32 -> bf16) ----
    // A[m=16mt+l][k=32ks+8*quad+j]; each element read exactly once per block.
    bf16x8 aX[4][4];
    const bf16x8 zf = {0,0,0,0,0,0,0,0};
    const float* xb = hs + (size_t)b*SEQ*CH + quad*8;
#pragma unroll
    for (int mt = 0; mt < 4; ++mt) {
        const int row = mt*16 + l;
        if (row < SEQ) {
            const float* xr = xb + row*CH;
#pragma unroll
            for (int ks = 0; ks < 4; ++ks)
                aX[mt][ks] = pack8(*(const float4*)(xr + ks*32),
                                   *(const float4*)(xr + ks*32 + 4));
        } else {
#pragma unroll
            for (int ks = 0; ks < 4; ++ks) aX[mt][ks] = zf;
        }
    }

    // ---- phase 1: QKV projection ----
    const float* Wmat[3] = {Wq, Wk, Wv};
    const float* Bvec[3] = {bq, bk, bv};
#pragma unroll
    for (int which = 0; which < 3; ++which) {
#pragma unroll
        for (int j = 0; j < 2; ++j) {
            const int col = (wave*2 + j)*16 + l;   // output channel
            const float* wr = Wmat[which] + (size_t)col*CH + quad*8;
            float4 w[8];
#pragma unroll
            for (int ks = 0; ks < 4; ++ks) {
                w[2*ks]   = *(const float4*)(wr + ks*32);
                w[2*ks+1] = *(const float4*)(wr + ks*32 + 4);
            }
            f32x4 acc[4] = {{0.f,0.f,0.f,0.f},{0.f,0.f,0.f,0.f},
                            {0.f,0.f,0.f,0.f},{0.f,0.f,0.f,0.f}};
#pragma unroll
            for (int ks = 0; ks < 4; ++ks) {
                const bf16x8 bw = pack8(w[2*ks], w[2*ks+1]);
#pragma unroll
                for (int mt = 0; mt < 4; ++mt)
                    acc[mt] = __builtin_amdgcn_mfma_f32_16x16x32_bf16(
                        aX[mt][ks], bw, acc[mt], 0, 0, 0);
            }
            const float bias = Bvec[which][col];
            if (which == 2) {
                // Vt[d][m], m = 16mt+4q+r contiguous -> packed 8 B store
#pragma unroll
                for (int mt = 0; mt < 4; ++mt) {
                    alignas(8) bf16 t4[4] = {
                        __float2bfloat16(acc[mt][0] + bias),
                        __float2bfloat16(acc[mt][1] + bias),
                        __float2bfloat16(acc[mt][2] + bias),
                        __float2bfloat16(acc[mt][3] + bias)};
                    *(uint2*)(sVt + col*LDP + mt*16 + quad*4) = *(const uint2*)t4;
                }
            } else {
                bf16* dst = (which == 0) ? sQ : sK;
#pragma unroll
                for (int mt = 0; mt < 4; ++mt)
#pragma unroll
                    for (int r = 0; r < 4; ++r)
                        dst[(mt*16 + quad*4 + r)*LDQ + col] =
                            __float2bfloat16(acc[mt][r] + bias);
            }
        }
    }

    // ---- epilogue prefetch buffers (mask + bias), 1-tile-ahead pipeline ----
    const int h = wave;
    float pm[2][16], pb[2][16];
    int   pi[2][16];
    auto prefetchMB = [&](int mt, int pbuf) {
#pragma unroll
        for (int r = 0; r < 4; ++r)
#pragma unroll
            for (int nt = 0; nt < 4; ++nt) {
                const int nq = mt*16 + quad*4 + r;
                const int mk = nt*16 + l;
                const int nqc = nq > SEQ-1 ? SEQ-1 : nq;
                const int mkc = mk > SEQ-1 ? SEQ-1 : mk;
                pm[pbuf][r*4+nt] = amask[(size_t)b*SEQ*SEQ + nqc*SEQ + mkc];
                if (USEWS)
                    pb[pbuf][r*4+nt] = bias_pad[h*4096 + nq*64 + mk];
                else
                    pi[pbuf][r*4+nt] = ridx[nqc*SEQ + mkc];
            }
    };
    prefetchMB(0, 0);                 // in flight across the barrier
    __syncthreads();                  // B1: Q/K/Vt visible

    // ---- phase 2: S = Q K^T ; softmax ; P -> LDS ----
    bf16x8 aQ[4], bK[4];
#pragma unroll
    for (int t = 0; t < 4; ++t) {
        aQ[t] = *(const bf16x8*)(sQ + (t*16 + l)*LDQ + h*DHD + quad*8);
        bK[t] = *(const bf16x8*)(sK + (t*16 + l)*LDQ + h*DHD + quad*8);
    }
    __syncthreads();                  // B2: frags in regs -> P may overwrite Q/K

    f32x4 S[4][4];
#pragma unroll
    for (int mt = 0; mt < 4; ++mt)
#pragma unroll
        for (int nt = 0; nt < 4; ++nt) {
            f32x4 z = {0.f,0.f,0.f,0.f};
            S[mt][nt] = __builtin_amdgcn_mfma_f32_16x16x32_bf16(aQ[mt], bK[nt], z, 0, 0, 0);
        }

    const float scale = 0.17677669529663687f; // 1/sqrt(32)
#pragma unroll
    for (int mt = 0; mt < 4; ++mt) {
        const int cur = mt & 1;
        if (mt < 3) prefetchMB(mt+1, cur^1);
        float bias_g[16];
        if (!USEWS) {
#pragma unroll
            for (int e = 0; e < 16; ++e) {
                int idx = pi[cur][e];
                idx = idx < 0 ? 0 : (idx > NTAB-1 ? NTAB-1 : idx);
                bias_g[e] = table[idx*NH + h];
            }
        }
#pragma unroll
        for (int r = 0; r < 4; ++r) {
            const int nq = mt*16 + quad*4 + r;
#pragma unroll
            for (int nt = 0; nt < 4; ++nt) {
                const int mk = nt*16 + l;
                float s;
                if (mk < SEQ) {
                    const float bvv = USEWS ? pb[cur][r*4+nt]
                                            : ((nq < SEQ) ? bias_g[r*4+nt] : 0.f);
                    s = S[mt][nt][r]*scale + bvv + pm[cur][r*4+nt];
                } else {
                    s = -30000.f;
                }
                S[mt][nt][r] = s;
            }
            float m = fmaxf(fmaxf(S[mt][0][r], S[mt][1][r]),
                            fmaxf(S[mt][2][r], S[mt][3][r]));
            m = fmaxf(m, __shfl_xor(m, 1));
            m = fmaxf(m, __shfl_xor(m, 2));
            m = fmaxf(m, __shfl_xor(m, 4));
            m = fmaxf(m, __shfl_xor(m, 8));
            float sum = 0.f;
#pragma unroll
            for (int nt = 0; nt < 4; ++nt) {
                float e = __expf(S[mt][nt][r] - m);
                S[mt][nt][r] = e;
                sum += e;
            }
            sum += __shfl_xor(sum, 1);
            sum += __shfl_xor(sum, 2);
            sum += __shfl_xor(sum, 4);
            sum += __shfl_xor(sum, 8);
            const float inv = 1.f / sum;
            if (nq < PROWS) {
#pragma unroll
                for (int nt = 0; nt < 4; ++nt)
                    sP[h*(PROWS*LDP) + nq*LDP + nt*16 + l] =
                        __float2bfloat16(S[mt][nt][r] * inv);
            }
        }
    }
    __syncthreads();                  // B3: P visible

    // ---- phase 3: O = P V ----
    bf16x8 aP[4][2], bV[2][2];
#pragma unroll
    for (int mt = 0; mt < 4; ++mt)
#pragma unroll
        for (int ks = 0; ks < 2; ++ks)
            aP[mt][ks] = *(const bf16x8*)(sP + h*(PROWS*LDP) + (mt*16 + l)*LDP + ks*32 + quad*8);
#pragma unroll
    for (int nt = 0; nt < 2; ++nt)
#pragma unroll
        for (int ks = 0; ks < 2; ++ks)
            bV[nt][ks] = *(const bf16x8*)(sVt + (h*DHD + nt*16 + l)*LDP + ks*32 + quad*8);

    f32x4 O[4][2] = {{{0.f,0.f,0.f,0.f},{0.f,0.f,0.f,0.f}},
                     {{0.f,0.f,0.f,0.f},{0.f,0.f,0.f,0.f}},
                     {{0.f,0.f,0.f,0.f},{0.f,0.f,0.f,0.f}},
                     {{0.f,0.f,0.f,0.f},{0.f,0.f,0.f,0.f}}};
#pragma unroll
    for (int mt = 0; mt < 4; ++mt)
#pragma unroll
        for (int nt = 0; nt < 2; ++nt)
#pragma unroll
            for (int ks = 0; ks < 2; ++ks)
                O[mt][nt] = __builtin_amdgcn_mfma_f32_16x16x32_bf16(
                    aP[mt][ks], bV[nt][ks], O[mt][nt], 0, 0, 0);

#pragma unroll
    for (int mt = 0; mt < 4; ++mt)
#pragma unroll
        for (int r = 0; r < 4; ++r) {
            const int nq = mt*16 + quad*4 + r;
            if (nq < SEQ) {
#pragma unroll
                for (int nt = 0; nt < 2; ++nt)
                    out[((size_t)b*SEQ + nq)*CH + h*DHD + nt*16 + l] = O[mt][nt][r];
            }
        }
}

extern "C" void kernel_launch(void* const* d_in, const int* in_sizes, int n_in,
                              void* d_out, int out_size, void* d_ws, size_t ws_size,
                              hipStream_t stream) {
    (void)n_in; (void)out_size;
    const int nwin = in_sizes[0] / (SEQ * CH);
    const bool usews = (ws_size >= (size_t)NH*64*64*sizeof(float)) && d_ws != nullptr;
    if (usews) {
        bias_precompute_kernel<<<dim3((NH*64*64 + 255)/256), 256, 0, stream>>>(
            (const float*)d_in[8], (const int*)d_in[9], (float*)d_ws);
        hipFuncSetAttribute(reinterpret_cast<const void*>(swin_attn_kernel<true>),
                            hipFuncAttributeMaxDynamicSharedMemorySize, SMEM_BYTES);
        swin_attn_kernel<true><<<dim3(nwin), dim3(256), SMEM_BYTES, stream>>>(
            (const float*)d_in[0], (const float*)d_in[1],
            (const float*)d_in[2], (const float*)d_in[3],
            (const float*)d_in[4], (const float*)d_in[5],
            (const float*)d_in[6], (const float*)d_in[7],
            (const float*)d_in[8], (const int*)d_in[9],
            (const float*)d_ws, (float*)d_out);
    } else {
        hipFuncSetAttribute(reinterpret_cast<const void*>(swin_attn_kernel<false>),
                            hipFuncAttributeMaxDynamicSharedMemorySize, SMEM_BYTES);
        swin_attn_kernel<false><<<dim3(nwin), dim3(256), SMEM_BYTES, stream>>>(
            (const float*)d_in[0], (const float*)d_in[1],
            (const float*)d_in[2], (const float*)d_in[3],
            (const float*)d_in[4], (const float*)d_in[5],
            (const float*)d_in[6], (const float*)d_in[7],
            (const float*)d_in[8], (const int*)d_in[9],
            nullptr, (float*)d_out);
    }
}